// Round 2
// baseline (829.608 us; speedup 1.0000x reference)
//
#include <hip/hip_runtime.h>
#include <stdint.h>

#define M_DIM 65536
#define N_DIM 1024
#define K_DIM 256
#define BM 128
#define BN 128
#define BK 64

typedef __attribute__((ext_vector_type(8))) short short8;
typedef __attribute__((ext_vector_type(16))) float float16;

__device__ __forceinline__ unsigned f2bf(float f) {
    unsigned u = __builtin_bit_cast(unsigned, f);
    u += 0x7FFFu + ((u >> 16) & 1u);   // round-to-nearest-even
    return u >> 16;
}

// Single fused kernel: out[m,n] = ||x_m||^2 - 2 x_m . w_n + ||w_n||^2
//   cross term via bf16 MFMA (w pre-scaled by -2 at convert time)
//   ||x||^2, ||w||^2 in fp32 from the original fp32 data (accuracy)
__global__ __launch_bounds__(256, 3)
void gemm_rbf(const float* __restrict__ x,
              const float* __restrict__ w,
              float* __restrict__ out) {
    __shared__ unsigned short xs[BM * BK];   // [row][64] bf16, chunk-swizzled
    __shared__ unsigned short ws[BN * BK];   // [col][64] bf16 of (-2w), chunk-swizzled
    __shared__ float xsq[BM];
    __shared__ float wsq_p[2][BN];

    const int tid  = threadIdx.x;
    const int lane = tid & 63;
    const int wave = tid >> 6;
    const int wy = wave >> 1, wx = wave & 1;  // 2x2 wave grid
    const int l31 = lane & 31;
    const int lhi = lane >> 5;

    // XCD-locality swizzle: assume xcd = bid & 7. Give each XCD a disjoint
    // m-range; sweep n fastest so concurrent blocks on one XCD share x in L2.
    const int bid = blockIdx.x;
    const int xcd = bid & 7;
    const int idx = bid >> 3;                 // 0..511 per-XCD sequence
    const int n0 = (idx & 7) * BN;
    const int m0 = ((xcd << 6) + (idx >> 3)) * BM;

    float16 acc[2][2];
    #pragma unroll
    for (int ty = 0; ty < 2; ++ty)
        #pragma unroll
        for (int tx = 0; tx < 2; ++tx)
            #pragma unroll
            for (int i = 0; i < 16; ++i) acc[ty][tx][i] = 0.f;

    float xpart[8];
    #pragma unroll
    for (int p = 0; p < 8; ++p) xpart[p] = 0.f;
    float wsq_r = 0.f;

    // staging thread roles
    const int xr = tid >> 4;    // x: base row 0..15 (rows xr + 16p)
    const int xc = tid & 15;    // x: float4 column group within 64-k chunk
    const int wcol = tid & 127; // w: column 0..127
    const int wkh  = tid >> 7;  // w: k-half (32 k each)

    // prefetch x for kt=0
    float4 xv[8];
    #pragma unroll
    for (int p = 0; p < 8; ++p)
        xv[p] = *(const float4*)(x + (size_t)(m0 + xr + p * 16) * K_DIM + xc * 4);

    for (int kt = 0; kt < 4; ++kt) {
        // w loads for this kt — registers only, issued BEFORE the barrier so
        // they overlap the previous iteration's MFMA section. Coalesced:
        // 64 consecutive cols per wave-half, 256B/inst, L2-resident (w = 1MB).
        float wv[4][8];
        #pragma unroll
        for (int c = 0; c < 4; ++c)
            #pragma unroll
            for (int j = 0; j < 8; ++j)
                wv[c][j] = w[(size_t)(kt * BK + wkh * 32 + c * 8 + j) * N_DIM + n0 + wcol];

        __syncthreads();   // previous MFMA readers done with LDS

        // xs: bf16-convert prefetched x, fold in fp32 sum-of-squares
        #pragma unroll
        for (int p = 0; p < 8; ++p) {
            const int r = xr + p * 16;
            const float4 v = xv[p];
            xpart[p] += v.x * v.x + v.y * v.y + v.z * v.z + v.w * v.w;
            uint2 pk;
            pk.x = f2bf(v.x) | (f2bf(v.y) << 16);
            pk.y = f2bf(v.z) | (f2bf(v.w) << 16);
            *(uint2*)((char*)xs + r * 128 + (((xc >> 1) ^ (r & 7)) << 4) + ((xc & 1) << 3)) = pk;
        }

        // prefetch x for kt+1 — in flight across the barrier + MFMA section
        if (kt < 3) {
            #pragma unroll
            for (int p = 0; p < 8; ++p)
                xv[p] = *(const float4*)(x + (size_t)(m0 + xr + p * 16) * K_DIM + (kt + 1) * BK + xc * 4);
        }

        // ws: convert w regs -> bf16(-2w), swizzled; fold in fp32 ||w||^2 partial
        #pragma unroll
        for (int c = 0; c < 4; ++c) {
            short8 pk;
            #pragma unroll
            for (int j = 0; j < 8; ++j) {
                const float v = wv[c][j];
                wsq_r += v * v;
                pk[j] = (short)f2bf(-2.0f * v);
            }
            *(short8*)((char*)ws + wcol * 128 + (((wkh * 4 + c) ^ (wcol & 7)) << 4)) = pk;
        }

        __syncthreads();

        // MFMA over this K-chunk: 4 steps of K=16
        const int arow0 = wy * 64 + l31;
        const int bcol0 = wx * 64 + l31;
        #pragma unroll
        for (int ks = 0; ks < 4; ++ks) {
            const int c = ks * 2 + lhi;
            short8 a[2], b[2];
            #pragma unroll
            for (int ty = 0; ty < 2; ++ty) {
                const int r = arow0 + ty * 32;
                a[ty] = *(const short8*)((const char*)xs + r * 128 + ((c ^ (r & 7)) << 4));
            }
            #pragma unroll
            for (int tx = 0; tx < 2; ++tx) {
                const int cc = bcol0 + tx * 32;
                b[tx] = *(const short8*)((const char*)ws + cc * 128 + ((c ^ (cc & 7)) << 4));
            }
            #pragma unroll
            for (int ty = 0; ty < 2; ++ty)
                #pragma unroll
                for (int tx = 0; tx < 2; ++tx)
                    acc[ty][tx] = __builtin_amdgcn_mfma_f32_32x32x16_bf16(
                        a[ty], b[tx], acc[ty][tx], 0, 0, 0);
        }
    }

    // reduce ||x_row||^2: 16 threads (consecutive lanes) share a row
    #pragma unroll
    for (int p = 0; p < 8; ++p) {
        float s = xpart[p];
        s += __shfl_xor(s, 1);
        s += __shfl_xor(s, 2);
        s += __shfl_xor(s, 4);
        s += __shfl_xor(s, 8);
        if (xc == 0) xsq[xr + p * 16] = s;
    }
    wsq_p[wkh][wcol] = wsq_r;
    __syncthreads();

    // epilogue: out = xsq[row] + acc + wsq[col]  (acc already has -2 folded)
    float wsqv[2];
    #pragma unroll
    for (int tx = 0; tx < 2; ++tx) {
        const int c = wx * 64 + tx * 32 + l31;
        wsqv[tx] = wsq_p[0][c] + wsq_p[1][c];
    }

    #pragma unroll
    for (int ty = 0; ty < 2; ++ty) {
        const int rbase = wy * 64 + ty * 32 + 4 * lhi;
        float xvv[16];
        #pragma unroll
        for (int i = 0; i < 16; ++i) xvv[i] = xsq[rbase + (i & 3) + 8 * (i >> 2)];
        #pragma unroll
        for (int tx = 0; tx < 2; ++tx) {
            const int col = n0 + wx * 64 + tx * 32 + l31;
            #pragma unroll
            for (int i = 0; i < 16; ++i) {
                const int row = m0 + rbase + (i & 3) + 8 * (i >> 2);
                out[(size_t)row * N_DIM + col] = xvv[i] + acc[ty][tx][i] + wsqv[tx];
            }
        }
    }
}

extern "C" void kernel_launch(void* const* d_in, const int* in_sizes, int n_in,
                              void* d_out, int out_size, void* d_ws, size_t ws_size,
                              hipStream_t stream) {
    const float* x = (const float*)d_in[0];
    const float* w = (const float*)d_in[1];
    float* out = (float*)d_out;
    (void)d_ws; (void)ws_size;

    gemm_rbf<<<(M_DIM / BM) * (N_DIM / BN), 256, 0, stream>>>(x, w, out);
}